// Round 1
// baseline (357.583 us; speedup 1.0000x reference)
//
#include <hip/hip_runtime.h>

#define SEQ 4096
#define EMB 768
#define HEADS 12
#define HD 64

typedef __attribute__((ext_vector_type(8))) short short8;
typedef __attribute__((ext_vector_type(8))) __bf16 bf16x8;
typedef __attribute__((ext_vector_type(4))) float f32x4;

static __device__ __forceinline__ unsigned short f2bf(float f) {
    unsigned int u = __builtin_bit_cast(unsigned int, f);
    unsigned int r = 0x7fffu + ((u >> 16) & 1u);
    u += r;
    return (unsigned short)(u >> 16);
}

static __device__ __forceinline__ f32x4 mfma_bf16(short8 a, short8 b, f32x4 c) {
    return __builtin_amdgcn_mfma_f32_16x16x32_bf16(
        __builtin_bit_cast(bf16x8, a), __builtin_bit_cast(bf16x8, b), c, 0, 0, 0);
}

// ---------------------------------------------------------------- convert
__global__ void convert_kernel(const float* __restrict__ x,
                               const float* __restrict__ wq,
                               const float* __restrict__ wk,
                               const float* __restrict__ wv,
                               const float* __restrict__ wo,
                               unsigned short* __restrict__ xb,
                               unsigned short* __restrict__ wqT,
                               unsigned short* __restrict__ wkT,
                               unsigned short* __restrict__ wvT,
                               unsigned short* __restrict__ woT) {
    int tid = blockIdx.x * blockDim.x + threadIdx.x;
    int stride = gridDim.x * blockDim.x;
    for (int i = tid; i < SEQ * EMB; i += stride) xb[i] = f2bf(x[i]);
    for (int i = tid; i < EMB * EMB; i += stride) {
        int n = i / EMB, k = i - n * EMB;  // wT[n][k] = w[k][n]
        int src = k * EMB + n;
        wqT[i] = f2bf(wq[src]);
        wkT[i] = f2bf(wk[src]);
        wvT[i] = f2bf(wv[src]);
        woT[i] = f2bf(wo[src]);
    }
}

// ---------------------------------------------------------------- GEMM
// C[M=4096][N=768] = A(bf16 [4096][768]) @ B + bias, with Bt[n][k] = B[k][n].
// MODE 0: bf16 head-major dst[(h*SEQ+m)*HD+d]   (Q, K)
// MODE 1: bf16 transposed  dst[(h*HD+d)*SEQ+m]  (V)
// MODE 2: fp32 dst[m*EMB+n]                     (final out)
template <int MODE>
__global__ __launch_bounds__(256) void gemm_kernel(const unsigned short* __restrict__ A,
                                                   const unsigned short* __restrict__ Bt,
                                                   const float* __restrict__ bias,
                                                   void* __restrict__ dst) {
    __shared__ __align__(16) unsigned short As[64 * 40];
    __shared__ __align__(16) unsigned short Bs[64 * 40];
    const int tid = threadIdx.x;
    const int wave = tid >> 6;
    const int lane = tid & 63;
    const int quad = lane >> 4;
    const int l16 = lane & 15;
    const int m0 = blockIdx.x * 64;
    const int n0 = blockIdx.y * 64;
    const int wm = (wave >> 1) * 32;
    const int wn = (wave & 1) * 32;
    const int srow = tid >> 2;
    const int scol = (tid & 3) * 8;

    f32x4 acc[2][2] = {};

    for (int k0 = 0; k0 < EMB; k0 += 32) {
        __syncthreads();
        *(uint4*)&As[srow * 40 + scol] = *(const uint4*)&A[(m0 + srow) * EMB + k0 + scol];
        *(uint4*)&Bs[srow * 40 + scol] = *(const uint4*)&Bt[(n0 + srow) * EMB + k0 + scol];
        __syncthreads();
        short8 a0 = *(const short8*)&As[(wm + l16) * 40 + quad * 8];
        short8 a1 = *(const short8*)&As[(wm + 16 + l16) * 40 + quad * 8];
        short8 b0 = *(const short8*)&Bs[(wn + l16) * 40 + quad * 8];
        short8 b1 = *(const short8*)&Bs[(wn + 16 + l16) * 40 + quad * 8];
        acc[0][0] = mfma_bf16(a0, b0, acc[0][0]);
        acc[0][1] = mfma_bf16(a0, b1, acc[0][1]);
        acc[1][0] = mfma_bf16(a1, b0, acc[1][0]);
        acc[1][1] = mfma_bf16(a1, b1, acc[1][1]);
    }

    for (int mt = 0; mt < 2; mt++)
        for (int nt = 0; nt < 2; nt++)
            for (int r = 0; r < 4; r++) {
                int m = m0 + wm + mt * 16 + quad * 4 + r;
                int n = n0 + wn + nt * 16 + l16;
                float v = acc[mt][nt][r] + bias[n];
                if (MODE == 0) {
                    int h = n >> 6, d = n & 63;
                    ((unsigned short*)dst)[(h * SEQ + m) * HD + d] = f2bf(v);
                } else if (MODE == 1) {
                    int h = n >> 6, d = n & 63;
                    ((unsigned short*)dst)[(h * HD + d) * SEQ + m] = f2bf(v);
                } else {
                    ((float*)dst)[m * EMB + n] = v;
                }
            }
}

// ---------------------------------------------------------------- attention
// grid: (SEQ/64 q-tiles, HEADS). block: 256 threads = 4 waves, 16 q-rows each.
__global__ __launch_bounds__(256) void attn_kernel(const unsigned short* __restrict__ Qb,
                                                   const unsigned short* __restrict__ Kb,
                                                   const unsigned short* __restrict__ Vtb,
                                                   unsigned short* __restrict__ ctxb) {
    __shared__ __align__(16) unsigned short Qs[64 * 72];
    __shared__ __align__(16) unsigned short Ks[64 * 72];
    __shared__ __align__(16) unsigned short Vs[64 * 72];   // Vs[d][kk]
    __shared__ __align__(16) unsigned short Ps[4][16 * 72];

    const int h = blockIdx.y;
    const int qt = blockIdx.x;
    const int qbase = qt * 64;
    const int tid = threadIdx.x;
    const int wave = tid >> 6;
    const int lane = tid & 63;
    const int quad = lane >> 4;
    const int l16 = lane & 15;

    const unsigned short* Qh = Qb + h * SEQ * HD;
    const unsigned short* Kh = Kb + h * SEQ * HD;
    const unsigned short* Vh = Vtb + h * HD * SEQ;

    {
        int row = tid >> 2, cg = (tid & 3) * 16;
        *(uint4*)&Qs[row * 72 + cg] = *(const uint4*)&Qh[(qbase + row) * HD + cg];
        *(uint4*)&Qs[row * 72 + cg + 8] = *(const uint4*)&Qh[(qbase + row) * HD + cg + 8];
    }
    __syncthreads();
    short8 aQ0 = *(const short8*)&Qs[(wave * 16 + l16) * 72 + quad * 8];
    short8 aQ1 = *(const short8*)&Qs[(wave * 16 + l16) * 72 + 32 + quad * 8];

    f32x4 O[4] = {};
    float m_i[4], l_i[4];
    for (int r = 0; r < 4; r++) { m_i[r] = -3.0e38f; l_i[r] = 0.f; }
    const float scale = 0.125f;  // 1/sqrt(64)

    for (int kt = 0; kt <= qt; kt++) {
        const int kbase = kt * 64;
        __syncthreads();  // prior iter's Vs/Ps reads done
        {
            int row = tid >> 2, cg = (tid & 3) * 16;
            *(uint4*)&Ks[row * 72 + cg] = *(const uint4*)&Kh[(kbase + row) * HD + cg];
            *(uint4*)&Ks[row * 72 + cg + 8] = *(const uint4*)&Kh[(kbase + row) * HD + cg + 8];
            *(uint4*)&Vs[row * 72 + cg] = *(const uint4*)&Vh[row * SEQ + kbase + cg];
            *(uint4*)&Vs[row * 72 + cg + 8] = *(const uint4*)&Vh[row * SEQ + kbase + cg + 8];
        }
        __syncthreads();

        // S = Q K^T  (16 q-rows x 64 k-cols per wave)
        f32x4 s[4];
        for (int nt = 0; nt < 4; nt++) {
            short8 b0 = *(const short8*)&Ks[(nt * 16 + l16) * 72 + quad * 8];
            short8 b1 = *(const short8*)&Ks[(nt * 16 + l16) * 72 + 32 + quad * 8];
            f32x4 z = {};
            z = mfma_bf16(aQ0, b0, z);
            z = mfma_bf16(aQ1, b1, z);
            s[nt] = z;
        }
        const bool diag = (kt == qt);
        for (int nt = 0; nt < 4; nt++) {
            int kk = kbase + nt * 16 + l16;
            for (int r = 0; r < 4; r++) {
                float v = s[nt][r] * scale;
                if (diag) {
                    int q = qbase + wave * 16 + quad * 4 + r;
                    if (kk > q) v = -INFINITY;
                }
                s[nt][r] = v;
            }
        }
        // online softmax
        float alpha[4];
        for (int r = 0; r < 4; r++) {
            float v = fmaxf(fmaxf(s[0][r], s[1][r]), fmaxf(s[2][r], s[3][r]));
            v = fmaxf(v, __shfl_xor(v, 1));
            v = fmaxf(v, __shfl_xor(v, 2));
            v = fmaxf(v, __shfl_xor(v, 4));
            v = fmaxf(v, __shfl_xor(v, 8));
            float mn = fmaxf(m_i[r], v);
            alpha[r] = __expf(m_i[r] - mn);
            m_i[r] = mn;
        }
        float rsum[4] = {0.f, 0.f, 0.f, 0.f};
        for (int nt = 0; nt < 4; nt++)
            for (int r = 0; r < 4; r++) {
                float p = __expf(s[nt][r] - m_i[r]);
                s[nt][r] = p;
                rsum[r] += p;
            }
        for (int r = 0; r < 4; r++) {
            float v = rsum[r];
            v += __shfl_xor(v, 1);
            v += __shfl_xor(v, 2);
            v += __shfl_xor(v, 4);
            v += __shfl_xor(v, 8);
            l_i[r] = l_i[r] * alpha[r] + v;
        }
        // P (C-layout) -> LDS, re-read in A-layout
        for (int nt = 0; nt < 4; nt++)
            for (int r = 0; r < 4; r++)
                Ps[wave][(quad * 4 + r) * 72 + nt * 16 + l16] = f2bf(s[nt][r]);
        for (int dt = 0; dt < 4; dt++)
            for (int r = 0; r < 4; r++)
                O[dt][r] *= alpha[r];
        __syncthreads();
        short8 aP0 = *(const short8*)&Ps[wave][l16 * 72 + quad * 8];
        short8 aP1 = *(const short8*)&Ps[wave][l16 * 72 + 32 + quad * 8];
        for (int dt = 0; dt < 4; dt++) {
            short8 b0 = *(const short8*)&Vs[(dt * 16 + l16) * 72 + quad * 8];
            short8 b1 = *(const short8*)&Vs[(dt * 16 + l16) * 72 + 32 + quad * 8];
            O[dt] = mfma_bf16(aP0, b0, O[dt]);
            O[dt] = mfma_bf16(aP1, b1, O[dt]);
        }
    }

    for (int dt = 0; dt < 4; dt++)
        for (int r = 0; r < 4; r++) {
            int q = qbase + wave * 16 + quad * 4 + r;
            int d = h * HD + dt * 16 + l16;
            ctxb[q * EMB + d] = f2bf(O[dt][r] / l_i[r]);
        }
}

// ---------------------------------------------------------------- launch
extern "C" void kernel_launch(void* const* d_in, const int* in_sizes, int n_in,
                              void* d_out, int out_size, void* d_ws, size_t ws_size,
                              hipStream_t stream) {
    const float* x = (const float*)d_in[0];
    const float* wq = (const float*)d_in[1];
    const float* bq = (const float*)d_in[2];
    const float* wk = (const float*)d_in[3];
    const float* bk = (const float*)d_in[4];
    const float* wv = (const float*)d_in[5];
    const float* bv = (const float*)d_in[6];
    const float* wo = (const float*)d_in[7];
    const float* bo = (const float*)d_in[8];

    unsigned short* ws = (unsigned short*)d_ws;
    unsigned short* xb = ws;                      // 4096*768
    unsigned short* wqT = xb + SEQ * EMB;         // 768*768 each
    unsigned short* wkT = wqT + EMB * EMB;
    unsigned short* wvT = wkT + EMB * EMB;
    unsigned short* woT = wvT + EMB * EMB;
    unsigned short* Qb = woT + EMB * EMB;         // 12*4096*64 each
    unsigned short* Kb = Qb + HEADS * SEQ * HD;
    unsigned short* Vtb = Kb + HEADS * SEQ * HD;
    unsigned short* ctxb = Vtb + HEADS * SEQ * HD;

    convert_kernel<<<dim3(512), dim3(256), 0, stream>>>(x, wq, wk, wv, wo, xb, wqT, wkT, wvT, woT);
    dim3 ggrid(SEQ / 64, EMB / 64);
    gemm_kernel<0><<<ggrid, 256, 0, stream>>>(xb, wqT, bq, Qb);
    gemm_kernel<0><<<ggrid, 256, 0, stream>>>(xb, wkT, bk, Kb);
    gemm_kernel<1><<<ggrid, 256, 0, stream>>>(xb, wvT, bv, Vtb);
    attn_kernel<<<dim3(SEQ / 64, HEADS), 256, 0, stream>>>(Qb, Kb, Vtb, ctxb);
    gemm_kernel<2><<<ggrid, 256, 0, stream>>>(ctxb, woT, bo, (float*)d_out);
}

// Round 2
// 218.912 us; speedup vs baseline: 1.6335x; 1.6335x over previous
//
#include <hip/hip_runtime.h>
#include <stdint.h>

#define SEQ 4096
#define EMB 768
#define HEADS 12
#define HD 64
#define NQT (SEQ / 64)

typedef __attribute__((ext_vector_type(8))) short short8;
typedef __attribute__((ext_vector_type(4))) short short4v;
typedef __attribute__((ext_vector_type(8))) __bf16 bf16x8;
typedef __attribute__((ext_vector_type(4))) __bf16 bf16x4;
typedef __attribute__((ext_vector_type(4))) float f32x4;

// scale * log2(e) folded into Q: (1/sqrt(64)) * 1.4426950408889634
#define QSCALE 0.18033688011112043f

static __device__ __forceinline__ unsigned short f2bf(float f) {
    unsigned int u = __builtin_bit_cast(unsigned int, f);
    unsigned int r = 0x7fffu + ((u >> 16) & 1u);
    u += r;
    return (unsigned short)(u >> 16);
}

static __device__ __forceinline__ f32x4 mfma32(short8 a, short8 b, f32x4 c) {
    return __builtin_amdgcn_mfma_f32_16x16x32_bf16(
        __builtin_bit_cast(bf16x8, a), __builtin_bit_cast(bf16x8, b), c, 0, 0, 0);
}

static __device__ __forceinline__ f32x4 mfma16(short4v a, short4v b, f32x4 c) {
#if __has_builtin(__builtin_amdgcn_mfma_f32_16x16x16_bf16)
    return __builtin_amdgcn_mfma_f32_16x16x16_bf16(
        __builtin_bit_cast(bf16x4, a), __builtin_bit_cast(bf16x4, b), c, 0, 0, 0);
#else
    return __builtin_amdgcn_mfma_f32_16x16x16bf16_1k(a, b, c, 0, 0, 0);
#endif
}

static __device__ __forceinline__ short4v pack4bf(float a, float b, float c, float d) {
#if __has_builtin(__builtin_amdgcn_cvt_pk_bf16_f32)
    typedef __attribute__((ext_vector_type(2))) __bf16 bf16x2;
    bf16x2 lo = __builtin_amdgcn_cvt_pk_bf16_f32(a, b);
    bf16x2 hi = __builtin_amdgcn_cvt_pk_bf16_f32(c, d);
    uint2 u = {__builtin_bit_cast(unsigned int, lo), __builtin_bit_cast(unsigned int, hi)};
    return __builtin_bit_cast(short4v, u);
#else
    short4v p;
    p[0] = (short)f2bf(a); p[1] = (short)f2bf(b);
    p[2] = (short)f2bf(c); p[3] = (short)f2bf(d);
    return p;
#endif
}

static __device__ __forceinline__ void load_lds16(const void* g, void* l) {
    __builtin_amdgcn_global_load_lds(
        (const __attribute__((address_space(1))) unsigned int*)(uintptr_t)g,
        (__attribute__((address_space(3))) unsigned int*)(uintptr_t)l, 16, 0, 0);
}

// ---------------------------------------------------------------- convert x
__global__ __launch_bounds__(256) void convert_x(const float* __restrict__ x,
                                                 unsigned short* __restrict__ xb) {
    int i = blockIdx.x * 256 + threadIdx.x;  // grid covers SEQ*EMB/4 exactly
    float4 v = ((const float4*)x)[i];
    ushort4 o = {f2bf(v.x), f2bf(v.y), f2bf(v.z), f2bf(v.w)};
    ((ushort4*)xb)[i] = o;
}

// ---------------------------------------------------------------- convert + transpose weights
// grid (12,12,4): z in {0,1,2} -> wqkvT row-block z*768; z==3 -> woT
__global__ __launch_bounds__(256) void convert_w(const float* __restrict__ wq,
                                                 const float* __restrict__ wk,
                                                 const float* __restrict__ wv,
                                                 const float* __restrict__ wo,
                                                 unsigned short* __restrict__ wqkvT,
                                                 unsigned short* __restrict__ woT) {
    __shared__ unsigned short Ls[64][72];
    const int z = blockIdx.z;
    const float* W = (z == 0) ? wq : (z == 1) ? wk : (z == 2) ? wv : wo;
    unsigned short* dst = (z < 3) ? (wqkvT + (size_t)z * EMB * EMB) : woT;
    const int k0 = blockIdx.x * 64, n0 = blockIdx.y * 64;
    const int r = threadIdx.x >> 2, c0 = (threadIdx.x & 3) * 16;
    for (int j = 0; j < 16; j += 4) {
        float4 v = *(const float4*)&W[(size_t)(k0 + r) * EMB + n0 + c0 + j];
        Ls[r][c0 + j] = f2bf(v.x);
        Ls[r][c0 + j + 1] = f2bf(v.y);
        Ls[r][c0 + j + 2] = f2bf(v.z);
        Ls[r][c0 + j + 3] = f2bf(v.w);
    }
    __syncthreads();
    unsigned short tmp[16];
    for (int j = 0; j < 16; j++) tmp[j] = Ls[c0 + j][r];
    *(uint4*)&dst[(size_t)(n0 + r) * EMB + k0 + c0] = *(uint4*)tmp;
    *(uint4*)&dst[(size_t)(n0 + r) * EMB + k0 + c0 + 8] = *(uint4*)(tmp + 8);
}

// ---------------------------------------------------------------- 128x128 GEMM (m97-style)
// C[M=4096][N] = A[4096][768] @ B, Bt[n][k]. MODE 0: fused QKV epilogue (N=2304).
// MODE 1: fp32 out + bias (N=768).
template <int MODE>
__global__ __launch_bounds__(256) void gemm128(const unsigned short* __restrict__ A,
                                               const unsigned short* __restrict__ Bt,
                                               const float* __restrict__ b0p,
                                               const float* __restrict__ b1p,
                                               const float* __restrict__ b2p,
                                               unsigned short* __restrict__ Qb,
                                               unsigned short* __restrict__ Kb,
                                               unsigned short* __restrict__ Vtb,
                                               float* __restrict__ outp) {
    __shared__ __align__(16) unsigned short As[128 * 32];
    __shared__ __align__(16) unsigned short Bs[128 * 32];
    const int tid = threadIdx.x;
    const int wave = tid >> 6, lane = tid & 63, quad = lane >> 4, l16 = lane & 15;
    const int m0 = blockIdx.x * 128, n0 = blockIdx.y * 128;
    const int wm = (wave >> 1) * 64, wn = (wave & 1) * 64;
    const int lrow = lane >> 2, lcol = (lane & 3) * 8;

    f32x4 acc[4][4] = {};

    for (int k0 = 0; k0 < EMB; k0 += 32) {
        __syncthreads();
        for (int t = 0; t < 2; t++) {
            int row = wave * 32 + t * 16 + lrow;
            load_lds16(&A[(size_t)(m0 + row) * EMB + k0 + lcol], &As[(wave * 2 + t) * 512]);
            load_lds16(&Bt[(size_t)(n0 + row) * EMB + k0 + lcol], &Bs[(wave * 2 + t) * 512]);
        }
        __syncthreads();
        short8 a[4], b[4];
        for (int i = 0; i < 4; i++) a[i] = *(const short8*)&As[(wm + i * 16 + l16) * 32 + quad * 8];
        for (int i = 0; i < 4; i++) b[i] = *(const short8*)&Bs[(wn + i * 16 + l16) * 32 + quad * 8];
        for (int i = 0; i < 4; i++)
            for (int j = 0; j < 4; j++) acc[i][j] = mfma32(a[i], b[j], acc[i][j]);
    }

    if (MODE == 1) {
        for (int i = 0; i < 4; i++)
            for (int j = 0; j < 4; j++) {
                int mbase = m0 + wm + i * 16 + quad * 4;
                int n = n0 + wn + j * 16 + l16;
                float bv = b0p[n];
                for (int r = 0; r < 4; r++) outp[(size_t)(mbase + r) * EMB + n] = acc[i][j][r] + bv;
            }
    } else {
        const int z = n0 / EMB;  // block-uniform: 0=Q, 1=K, 2=V
        const float* bias = (z == 0) ? b0p : (z == 1) ? b1p : b2p;
        for (int i = 0; i < 4; i++)
            for (int j = 0; j < 4; j++) {
                int mbase = m0 + wm + i * 16 + quad * 4;
                int n = n0 + wn + j * 16 + l16;
                int nn = n - z * EMB;
                int h = nn >> 6, d = nn & 63;
                float bv = bias[nn];
                if (z == 0) {
                    for (int r = 0; r < 4; r++)
                        Qb[(size_t)(h * SEQ + mbase + r) * HD + d] =
                            f2bf((acc[i][j][r] + bv) * QSCALE);
                } else if (z == 1) {
                    for (int r = 0; r < 4; r++)
                        Kb[(size_t)(h * SEQ + mbase + r) * HD + d] = f2bf(acc[i][j][r] + bv);
                } else {
                    ushort4 pk;
                    pk.x = f2bf(acc[i][j][0] + bv);
                    pk.y = f2bf(acc[i][j][1] + bv);
                    pk.z = f2bf(acc[i][j][2] + bv);
                    pk.w = f2bf(acc[i][j][3] + bv);
                    *(ushort4*)&Vtb[(size_t)(h * HD + d) * SEQ + mbase] = pk;
                }
            }
    }
}

// ---------------------------------------------------------------- attention
// 1D grid of 768 blocks, longest q-tiles dispatched first, heads fastest.
// Block = 4 waves; wave owns 16 q-rows (q = l16). S computed transposed
// (K as A-frag, Q as B-frag) so P exits in the exact B-frag layout of
// mfma_16x16x16 for O^T = V^T P^T — no LDS round-trip, 2-shuffle reductions.
__global__ __launch_bounds__(256) void attn_kernel(const unsigned short* __restrict__ Qb,
                                                   const unsigned short* __restrict__ Kb,
                                                   const unsigned short* __restrict__ Vtb,
                                                   unsigned short* __restrict__ ctxb) {
    __shared__ __align__(16) unsigned short Qs[64 * 72];
    __shared__ __align__(16) unsigned short Ks[64 * 72];
    __shared__ __align__(16) unsigned short Vs[64 * 72];  // Vs[d][k]

    const int bid = blockIdx.x;
    const int h = bid % HEADS;
    const int qt = (NQT - 1) - bid / HEADS;  // long blocks first
    const int qbase = qt * 64;
    const int tid = threadIdx.x;
    const int wave = tid >> 6, lane = tid & 63, quad = lane >> 4, l16 = lane & 15;

    const unsigned short* Qh = Qb + (size_t)h * SEQ * HD;
    const unsigned short* Kh = Kb + (size_t)h * SEQ * HD;
    const unsigned short* Vh = Vtb + (size_t)h * HD * SEQ;

    const int row = tid >> 2, cg = (tid & 3) * 16;
    *(uint4*)&Qs[row * 72 + cg] = *(const uint4*)&Qh[(size_t)(qbase + row) * HD + cg];
    *(uint4*)&Qs[row * 72 + cg + 8] = *(const uint4*)&Qh[(size_t)(qbase + row) * HD + cg + 8];
    __syncthreads();
    const short8 bQ0 = *(const short8*)&Qs[(wave * 16 + l16) * 72 + quad * 8];
    const short8 bQ1 = *(const short8*)&Qs[(wave * 16 + l16) * 72 + 32 + quad * 8];
    const int q = qbase + wave * 16 + l16;

    f32x4 O[4] = {};
    float m_i = -3.0e38f, l_i = 0.f;

    uint4 kr0, kr1, vr0, vr1;
    {
        kr0 = *(const uint4*)&Kh[(size_t)row * HD + cg];
        kr1 = *(const uint4*)&Kh[(size_t)row * HD + cg + 8];
        vr0 = *(const uint4*)&Vh[(size_t)row * SEQ + cg];
        vr1 = *(const uint4*)&Vh[(size_t)row * SEQ + cg + 8];
    }

    for (int kt = 0; kt <= qt; kt++) {
        const int kbase = kt * 64;
        __syncthreads();  // prior iter's Ks/Vs reads done
        *(uint4*)&Ks[row * 72 + cg] = kr0;
        *(uint4*)&Ks[row * 72 + cg + 8] = kr1;
        *(uint4*)&Vs[row * 72 + cg] = vr0;
        *(uint4*)&Vs[row * 72 + cg + 8] = vr1;
        if (kt < qt) {  // prefetch next tile during compute
            const int nb = kbase + 64;
            kr0 = *(const uint4*)&Kh[(size_t)(nb + row) * HD + cg];
            kr1 = *(const uint4*)&Kh[(size_t)(nb + row) * HD + cg + 8];
            vr0 = *(const uint4*)&Vh[(size_t)row * SEQ + nb + cg];
            vr1 = *(const uint4*)&Vh[(size_t)row * SEQ + nb + cg + 8];
        }
        __syncthreads();

        // S^T tiles: lane holds q=l16 (col), k=kbase+nt*16+quad*4+r (row)
        f32x4 st[4];
        for (int nt = 0; nt < 4; nt++) {
            short8 aK0 = *(const short8*)&Ks[(nt * 16 + l16) * 72 + quad * 8];
            short8 aK1 = *(const short8*)&Ks[(nt * 16 + l16) * 72 + 32 + quad * 8];
            f32x4 z = {};
            z = mfma32(aK0, bQ0, z);
            z = mfma32(aK1, bQ1, z);
            st[nt] = z;
        }
        if (kt == qt) {  // causal mask on diagonal tile
            for (int nt = 0; nt < 4; nt++)
                for (int r = 0; r < 4; r++)
                    if (kbase + nt * 16 + quad * 4 + r > q) st[nt][r] = -INFINITY;
        }
        // online softmax over k (across r, nt, quads)
        float mx = -3.0e38f;
        for (int nt = 0; nt < 4; nt++)
            for (int r = 0; r < 4; r++) mx = fmaxf(mx, st[nt][r]);
        mx = fmaxf(mx, __shfl_xor(mx, 16));
        mx = fmaxf(mx, __shfl_xor(mx, 32));
        const float mn = fmaxf(m_i, mx);
        const float alpha = __builtin_amdgcn_exp2f(m_i - mn);
        m_i = mn;
        float rs = 0.f;
        short4v pk[4];
        for (int nt = 0; nt < 4; nt++) {
            float p0 = __builtin_amdgcn_exp2f(st[nt][0] - mn);
            float p1 = __builtin_amdgcn_exp2f(st[nt][1] - mn);
            float p2 = __builtin_amdgcn_exp2f(st[nt][2] - mn);
            float p3 = __builtin_amdgcn_exp2f(st[nt][3] - mn);
            rs += p0 + p1 + p2 + p3;
            pk[nt] = pack4bf(p0, p1, p2, p3);
        }
        rs += __shfl_xor(rs, 16);
        rs += __shfl_xor(rs, 32);
        l_i = l_i * alpha + rs;
        for (int dt = 0; dt < 4; dt++)
            for (int r = 0; r < 4; r++) O[dt][r] *= alpha;
        // O^T += V^T P^T : A = Vs rows (d=l16), B = pk (in-register)
        for (int dt = 0; dt < 4; dt++)
            for (int nt = 0; nt < 4; nt++) {
                short4v av = *(const short4v*)&Vs[(dt * 16 + l16) * 72 + nt * 16 + quad * 4];
                O[dt] = mfma16(av, pk[nt], O[dt]);
            }
    }

    const float inv = 1.f / l_i;
    for (int dt = 0; dt < 4; dt++) {
        ushort4 o;
        o.x = f2bf(O[dt][0] * inv);
        o.y = f2bf(O[dt][1] * inv);
        o.z = f2bf(O[dt][2] * inv);
        o.w = f2bf(O[dt][3] * inv);
        *(ushort4*)&ctxb[(size_t)q * EMB + h * HD + dt * 16 + quad * 4] = o;
    }
}

// ---------------------------------------------------------------- launch
extern "C" void kernel_launch(void* const* d_in, const int* in_sizes, int n_in,
                              void* d_out, int out_size, void* d_ws, size_t ws_size,
                              hipStream_t stream) {
    const float* x = (const float*)d_in[0];
    const float* wq = (const float*)d_in[1];
    const float* bq = (const float*)d_in[2];
    const float* wk = (const float*)d_in[3];
    const float* bk = (const float*)d_in[4];
    const float* wv = (const float*)d_in[5];
    const float* bv = (const float*)d_in[6];
    const float* wo = (const float*)d_in[7];
    const float* bo = (const float*)d_in[8];

    unsigned short* ws = (unsigned short*)d_ws;
    unsigned short* xb = ws;                          // 4096*768
    unsigned short* wqkvT = xb + SEQ * EMB;           // 2304*768
    unsigned short* woT = wqkvT + 3 * EMB * EMB;      // 768*768
    unsigned short* Qb = woT + EMB * EMB;             // 12*4096*64 each
    unsigned short* Kb = Qb + HEADS * SEQ * HD;
    unsigned short* Vtb = Kb + HEADS * SEQ * HD;
    unsigned short* ctxb = Vtb + HEADS * SEQ * HD;

    convert_x<<<dim3(SEQ * EMB / 4 / 256), 256, 0, stream>>>(x, xb);
    convert_w<<<dim3(12, 12, 4), 256, 0, stream>>>(wq, wk, wv, wo, wqkvT, woT);
    gemm128<0><<<dim3(SEQ / 128, 3 * EMB / 128), 256, 0, stream>>>(
        xb, wqkvT, bq, bk, bv, Qb, Kb, Vtb, nullptr);
    attn_kernel<<<dim3(NQT * HEADS), 256, 0, stream>>>(Qb, Kb, Vtb, ctxb);
    gemm128<1><<<dim3(SEQ / 128, EMB / 128), 256, 0, stream>>>(
        ctxb, woT, bo, nullptr, nullptr, nullptr, nullptr, nullptr, (float*)d_out);
}

// Round 4
// 209.242 us; speedup vs baseline: 1.7089x; 1.0462x over previous
//
#include <hip/hip_runtime.h>
#include <stdint.h>

#define SEQ 4096
#define EMB 768
#define HEADS 12
#define HD 64
#define NQT (SEQ / 64)

typedef __attribute__((ext_vector_type(8))) short short8;
typedef __attribute__((ext_vector_type(4))) short short4v;
typedef __attribute__((ext_vector_type(8))) __bf16 bf16x8;
typedef __attribute__((ext_vector_type(4))) __bf16 bf16x4;
typedef __attribute__((ext_vector_type(4))) float f32x4;

// scale * log2(e) folded into Q: (1/sqrt(64)) * 1.4426950408889634
#define QSCALE 0.18033688011112043f

static __device__ __forceinline__ unsigned short f2bf(float f) {
    unsigned int u = __builtin_bit_cast(unsigned int, f);
    unsigned int r = 0x7fffu + ((u >> 16) & 1u);
    u += r;
    return (unsigned short)(u >> 16);
}

static __device__ __forceinline__ f32x4 mfma32(short8 a, short8 b, f32x4 c) {
    return __builtin_amdgcn_mfma_f32_16x16x32_bf16(
        __builtin_bit_cast(bf16x8, a), __builtin_bit_cast(bf16x8, b), c, 0, 0, 0);
}

static __device__ __forceinline__ f32x4 mfma16(short4v a, short4v b, f32x4 c) {
#if __has_builtin(__builtin_amdgcn_mfma_f32_16x16x16_bf16)
    return __builtin_amdgcn_mfma_f32_16x16x16_bf16(
        __builtin_bit_cast(bf16x4, a), __builtin_bit_cast(bf16x4, b), c, 0, 0, 0);
#else
    return __builtin_amdgcn_mfma_f32_16x16x16bf16_1k(a, b, c, 0, 0, 0);
#endif
}

static __device__ __forceinline__ short4v pack4bf(float a, float b, float c, float d) {
#if __has_builtin(__builtin_amdgcn_cvt_pk_bf16_f32)
    typedef __attribute__((ext_vector_type(2))) __bf16 bf16x2;
    bf16x2 lo = __builtin_amdgcn_cvt_pk_bf16_f32(a, b);
    bf16x2 hi = __builtin_amdgcn_cvt_pk_bf16_f32(c, d);
    uint2 u = {__builtin_bit_cast(unsigned int, lo), __builtin_bit_cast(unsigned int, hi)};
    return __builtin_bit_cast(short4v, u);
#else
    short4v p;
    p[0] = (short)f2bf(a); p[1] = (short)f2bf(b);
    p[2] = (short)f2bf(c); p[3] = (short)f2bf(d);
    return p;
#endif
}

static __device__ __forceinline__ void load_lds16(const void* g, void* l) {
    __builtin_amdgcn_global_load_lds(
        (const __attribute__((address_space(1))) unsigned int*)(uintptr_t)g,
        (__attribute__((address_space(3))) unsigned int*)(uintptr_t)l, 16, 0, 0);
}

// ---------------------------------------------------------------- convert x
__global__ __launch_bounds__(256) void convert_x(const float* __restrict__ x,
                                                 unsigned short* __restrict__ xb) {
    int i = blockIdx.x * 256 + threadIdx.x;  // grid covers SEQ*EMB/4 exactly
    float4 v = ((const float4*)x)[i];
    ushort4 o = {f2bf(v.x), f2bf(v.y), f2bf(v.z), f2bf(v.w)};
    ((ushort4*)xb)[i] = o;
}

// ---------------------------------------------------------------- convert + transpose weights
// grid (12,12,4). fp32 LDS tile [64][65]: scalar LDS writes and transposed
// reads are both bank-conflict-free.
__global__ __launch_bounds__(256) void convert_w(const float* __restrict__ wq,
                                                 const float* __restrict__ wk,
                                                 const float* __restrict__ wv,
                                                 const float* __restrict__ wo,
                                                 unsigned short* __restrict__ wqkvT,
                                                 unsigned short* __restrict__ woT) {
    __shared__ float Ls[64][65];
    const int z = blockIdx.z;
    const float* W = (z == 0) ? wq : (z == 1) ? wk : (z == 2) ? wv : wo;
    unsigned short* dst = (z < 3) ? (wqkvT + (size_t)z * EMB * EMB) : woT;
    const int k0 = blockIdx.x * 64, n0 = blockIdx.y * 64;
    const int r = threadIdx.x >> 2, c0 = (threadIdx.x & 3) * 16;
    for (int j = 0; j < 16; j += 4) {
        float4 v = *(const float4*)&W[(size_t)(k0 + r) * EMB + n0 + c0 + j];
        Ls[r][c0 + j] = v.x;
        Ls[r][c0 + j + 1] = v.y;
        Ls[r][c0 + j + 2] = v.z;
        Ls[r][c0 + j + 3] = v.w;
    }
    __syncthreads();
    unsigned short tmp[16];
    for (int j = 0; j < 16; j++) tmp[j] = f2bf(Ls[c0 + j][r]);
    *(uint4*)&dst[(size_t)(n0 + r) * EMB + k0 + c0] = *(uint4*)tmp;
    *(uint4*)&dst[(size_t)(n0 + r) * EMB + k0 + c0 + 8] = *(uint4*)(tmp + 8);
}

// ---------------------------------------------------------------- 128x128 GEMM (m97-style)
// MODE 0: fused QKV (N=2304): Q,K -> QKb natural [m][1536] (Q pre-scaled),
//         V -> Vtb transposed [(h*HD+d)][m].  MODE 1: fp32 out + bias.
template <int MODE>
__global__ __launch_bounds__(256) void gemm128(const unsigned short* __restrict__ A,
                                               const unsigned short* __restrict__ Bt,
                                               const float* __restrict__ b0p,
                                               const float* __restrict__ b1p,
                                               const float* __restrict__ b2p,
                                               unsigned short* __restrict__ QKb,
                                               unsigned short* __restrict__ Vtb,
                                               float* __restrict__ outp) {
    __shared__ __align__(16) unsigned short As[128 * 32];
    __shared__ __align__(16) unsigned short Bs[128 * 32];
    const int tid = threadIdx.x;
    const int wave = tid >> 6, lane = tid & 63, quad = lane >> 4, l16 = lane & 15;
    const int m0 = blockIdx.x * 128, n0 = blockIdx.y * 128;
    const int wm = (wave >> 1) * 64, wn = (wave & 1) * 64;
    const int lrow = lane >> 2, lcol = (lane & 3) * 8;

    f32x4 acc[4][4] = {};

    for (int k0 = 0; k0 < EMB; k0 += 32) {
        __syncthreads();
        for (int t = 0; t < 2; t++) {
            int row = wave * 32 + t * 16 + lrow;
            load_lds16(&A[(size_t)(m0 + row) * EMB + k0 + lcol], &As[(wave * 2 + t) * 512]);
            load_lds16(&Bt[(size_t)(n0 + row) * EMB + k0 + lcol], &Bs[(wave * 2 + t) * 512]);
        }
        __syncthreads();
        short8 a[4], b[4];
        for (int i = 0; i < 4; i++) a[i] = *(const short8*)&As[(wm + i * 16 + l16) * 32 + quad * 8];
        for (int i = 0; i < 4; i++) b[i] = *(const short8*)&Bs[(wn + i * 16 + l16) * 32 + quad * 8];
        for (int i = 0; i < 4; i++)
            for (int j = 0; j < 4; j++) acc[i][j] = mfma32(a[i], b[j], acc[i][j]);
    }

    if (MODE == 1) {
        for (int i = 0; i < 4; i++)
            for (int j = 0; j < 4; j++) {
                int mbase = m0 + wm + i * 16 + quad * 4;
                int n = n0 + wn + j * 16 + l16;
                float bv = b0p[n];
                for (int r = 0; r < 4; r++) outp[(size_t)(mbase + r) * EMB + n] = acc[i][j][r] + bv;
            }
    } else {
        const int z = n0 / EMB;  // block-uniform: 0=Q, 1=K, 2=V
        if (z < 2) {
            const float* bias = z ? b1p : b0p;
            const float sc = z ? 1.0f : QSCALE;
            for (int i = 0; i < 4; i++)
                for (int j = 0; j < 4; j++) {
                    int mbase = m0 + wm + i * 16 + quad * 4;
                    int n = n0 + wn + j * 16 + l16;   // 0..1535, natural col
                    float bv = bias[n - z * EMB];
                    for (int r = 0; r < 4; r++)
                        QKb[(size_t)(mbase + r) * 1536 + n] = f2bf((acc[i][j][r] + bv) * sc);
                }
        } else {
            for (int i = 0; i < 4; i++)
                for (int j = 0; j < 4; j++) {
                    int mbase = m0 + wm + i * 16 + quad * 4;
                    int nn = n0 + wn + j * 16 + l16 - 2 * EMB;
                    int h = nn >> 6, d = nn & 63;
                    float bv = b2p[nn];
                    ushort4 pk;
                    pk.x = f2bf(acc[i][j][0] + bv);
                    pk.y = f2bf(acc[i][j][1] + bv);
                    pk.z = f2bf(acc[i][j][2] + bv);
                    pk.w = f2bf(acc[i][j][3] + bv);
                    // Vtb[(h*HD + d)][m]  (R3 bug was h*SEQ + d*SEQ)
                    *(ushort4*)&Vtb[(size_t)(h * HD + d) * SEQ + mbase] = pk;
                }
        }
    }
}

// ---------------------------------------------------------------- attention
// 1152 blocks: bid<768 -> split blocks (qt>=32, s=bid&1, half k-range each),
// writing unnormalized bf16 O-partials + (m,l). bid>=768 -> qt<32, full range,
// writes ctxb directly. Whole grid co-resident (5 blocks/CU LDS cap).
__global__ __launch_bounds__(256) void attn_kernel(const unsigned short* __restrict__ QKb,
                                                   const unsigned short* __restrict__ Vtb,
                                                   unsigned short* __restrict__ ctxb,
                                                   unsigned short* __restrict__ Op,
                                                   float* __restrict__ mArr,
                                                   float* __restrict__ lArr) {
    __shared__ __align__(16) unsigned short Qs[64 * 72];
    __shared__ __align__(16) unsigned short Ks[64 * 72];
    __shared__ __align__(16) unsigned short Vs[64 * 72];  // Vs[d][k]

    const int bid = blockIdx.x;
    int s, h, qt, kb, ke;
    if (bid < 768) {
        s = bid & 1;
        int idx = bid >> 1;
        qt = 63 - idx / 12;
        h = idx % 12;
        int h0 = (qt + 2) >> 1;
        kb = s ? h0 : 0;
        ke = s ? qt : h0 - 1;
    } else {
        s = -1;
        int idx = bid - 768;
        qt = 31 - idx / 12;
        h = idx % 12;
        kb = 0;
        ke = qt;
    }
    const int qbase = qt * 64;
    const int tid = threadIdx.x;
    const int wave = tid >> 6, lane = tid & 63, quad = lane >> 4, l16 = lane & 15;

    const unsigned short* Qg = QKb + (size_t)h * HD;           // row stride 1536
    const unsigned short* Kg = QKb + (size_t)(EMB + h * HD);   // row stride 1536
    const unsigned short* Vh = Vtb + (size_t)h * HD * SEQ;     // [d][m]

    const int row = tid >> 2, cg = (tid & 3) * 16;
    *(uint4*)&Qs[row * 72 + cg] = *(const uint4*)&Qg[(size_t)(qbase + row) * 1536 + cg];
    *(uint4*)&Qs[row * 72 + cg + 8] = *(const uint4*)&Qg[(size_t)(qbase + row) * 1536 + cg + 8];
    __syncthreads();
    const short8 bQ0 = *(const short8*)&Qs[(wave * 16 + l16) * 72 + quad * 8];
    const short8 bQ1 = *(const short8*)&Qs[(wave * 16 + l16) * 72 + 32 + quad * 8];
    const int q = qbase + wave * 16 + l16;

    f32x4 O[4] = {};
    float m_i = -3.0e38f, l_i = 0.f;

    uint4 kr0, kr1, vr0, vr1;
    {
        const int kb64 = kb * 64;
        kr0 = *(const uint4*)&Kg[(size_t)(kb64 + row) * 1536 + cg];
        kr1 = *(const uint4*)&Kg[(size_t)(kb64 + row) * 1536 + cg + 8];
        vr0 = *(const uint4*)&Vh[(size_t)row * SEQ + kb64 + cg];
        vr1 = *(const uint4*)&Vh[(size_t)row * SEQ + kb64 + cg + 8];
    }

    for (int kt = kb; kt <= ke; kt++) {
        const int kbase = kt * 64;
        __syncthreads();  // prior iter's Ks/Vs reads done
        *(uint4*)&Ks[row * 72 + cg] = kr0;
        *(uint4*)&Ks[row * 72 + cg + 8] = kr1;
        *(uint4*)&Vs[row * 72 + cg] = vr0;
        *(uint4*)&Vs[row * 72 + cg + 8] = vr1;
        if (kt < ke) {  // prefetch next tile during compute
            const int nb = kbase + 64;
            kr0 = *(const uint4*)&Kg[(size_t)(nb + row) * 1536 + cg];
            kr1 = *(const uint4*)&Kg[(size_t)(nb + row) * 1536 + cg + 8];
            vr0 = *(const uint4*)&Vh[(size_t)row * SEQ + nb + cg];
            vr1 = *(const uint4*)&Vh[(size_t)row * SEQ + nb + cg + 8];
        }
        __syncthreads();

        // S^T tiles: lane holds q=l16 (col), k=kbase+nt*16+quad*4+r (row)
        f32x4 st[4];
        for (int nt = 0; nt < 4; nt++) {
            short8 aK0 = *(const short8*)&Ks[(nt * 16 + l16) * 72 + quad * 8];
            short8 aK1 = *(const short8*)&Ks[(nt * 16 + l16) * 72 + 32 + quad * 8];
            f32x4 z = {};
            z = mfma32(aK0, bQ0, z);
            z = mfma32(aK1, bQ1, z);
            st[nt] = z;
        }
        if (kt == qt) {  // causal mask on diagonal tile
            for (int nt = 0; nt < 4; nt++)
                for (int r = 0; r < 4; r++)
                    if (kbase + nt * 16 + quad * 4 + r > q) st[nt][r] = -INFINITY;
        }
        // online softmax over k (across r, nt, quads)
        float mx = -3.0e38f;
        for (int nt = 0; nt < 4; nt++)
            for (int r = 0; r < 4; r++) mx = fmaxf(mx, st[nt][r]);
        mx = fmaxf(mx, __shfl_xor(mx, 16));
        mx = fmaxf(mx, __shfl_xor(mx, 32));
        const bool inc = mx > m_i;
        if (__ballot(inc)) {
            const float mn = inc ? mx : m_i;
            const float alpha = __builtin_amdgcn_exp2f(m_i - mn);
            m_i = mn;
            l_i *= alpha;
            for (int dt = 0; dt < 4; dt++)
                for (int r = 0; r < 4; r++) O[dt][r] *= alpha;
        }
        float rs = 0.f;
        short4v pk[4];
        for (int nt = 0; nt < 4; nt++) {
            float p0 = __builtin_amdgcn_exp2f(st[nt][0] - m_i);
            float p1 = __builtin_amdgcn_exp2f(st[nt][1] - m_i);
            float p2 = __builtin_amdgcn_exp2f(st[nt][2] - m_i);
            float p3 = __builtin_amdgcn_exp2f(st[nt][3] - m_i);
            rs += p0 + p1 + p2 + p3;
            pk[nt] = pack4bf(p0, p1, p2, p3);
        }
        rs += __shfl_xor(rs, 16);
        rs += __shfl_xor(rs, 32);
        l_i += rs;
        // O^T += V^T P^T : A = Vs rows (d=l16), B = pk (in-register)
        for (int dt = 0; dt < 4; dt++)
            for (int nt = 0; nt < 4; nt++) {
                short4v av = *(const short4v*)&Vs[(dt * 16 + l16) * 72 + nt * 16 + quad * 4];
                O[dt] = mfma16(av, pk[nt], O[dt]);
            }
    }

    const int ql = wave * 16 + l16;
    if (s < 0) {
        const float inv = 1.f / l_i;
        for (int dt = 0; dt < 4; dt++) {
            ushort4 o;
            o.x = f2bf(O[dt][0] * inv);
            o.y = f2bf(O[dt][1] * inv);
            o.z = f2bf(O[dt][2] * inv);
            o.w = f2bf(O[dt][3] * inv);
            *(ushort4*)&ctxb[(size_t)q * EMB + h * HD + dt * 16 + quad * 4] = o;
        }
    } else {
        const int pb = (s * HEADS + h) * 32 + (qt - 32);
        for (int dt = 0; dt < 4; dt++) {
            ushort4 o;
            o.x = f2bf(O[dt][0]);
            o.y = f2bf(O[dt][1]);
            o.z = f2bf(O[dt][2]);
            o.w = f2bf(O[dt][3]);
            *(ushort4*)&Op[(size_t)pb * 4096 + ql * 64 + dt * 16 + quad * 4] = o;
        }
        if (quad == 0) {
            mArr[pb * 64 + ql] = m_i;
            lArr[pb * 64 + ql] = l_i;
        }
    }
}

// ---------------------------------------------------------------- merge (qt>=32)
__global__ __launch_bounds__(256) void merge_kernel(const unsigned short* __restrict__ Op,
                                                    const float* __restrict__ mArr,
                                                    const float* __restrict__ lArr,
                                                    unsigned short* __restrict__ ctxb) {
    const int idx = blockIdx.x;  // 0..383
    const int qt = 32 + idx / HEADS;
    const int h = idx % HEADS;
    const int q = threadIdx.x >> 2, d0 = (threadIdx.x & 3) * 16;
    const int pb0 = h * 32 + (qt - 32);
    const int pb1 = (HEADS + h) * 32 + (qt - 32);
    const float m0 = mArr[pb0 * 64 + q], m1 = mArr[pb1 * 64 + q];
    const float l0 = lArr[pb0 * 64 + q], l1 = lArr[pb1 * 64 + q];
    const float M = fmaxf(m0, m1);
    float a0 = __builtin_amdgcn_exp2f(m0 - M);
    float a1 = __builtin_amdgcn_exp2f(m1 - M);
    const float inv = 1.f / (a0 * l0 + a1 * l1);
    a0 *= inv;
    a1 *= inv;
    for (int jj = 0; jj < 16; jj += 8) {
        uint4 u0 = *(const uint4*)&Op[(size_t)pb0 * 4096 + q * 64 + d0 + jj];
        uint4 u1 = *(const uint4*)&Op[(size_t)pb1 * 4096 + q * 64 + d0 + jj];
        const unsigned short* p0 = (const unsigned short*)&u0;
        const unsigned short* p1 = (const unsigned short*)&u1;
        unsigned short o[8];
        for (int t = 0; t < 8; t++) {
            float f0 = __builtin_bit_cast(float, (unsigned int)p0[t] << 16);
            float f1 = __builtin_bit_cast(float, (unsigned int)p1[t] << 16);
            o[t] = f2bf(a0 * f0 + a1 * f1);
        }
        *(uint4*)&ctxb[(size_t)(qt * 64 + q) * EMB + h * HD + d0 + jj] = *(uint4*)o;
    }
}

// ---------------------------------------------------------------- launch
extern "C" void kernel_launch(void* const* d_in, const int* in_sizes, int n_in,
                              void* d_out, int out_size, void* d_ws, size_t ws_size,
                              hipStream_t stream) {
    const float* x = (const float*)d_in[0];
    const float* wq = (const float*)d_in[1];
    const float* bq = (const float*)d_in[2];
    const float* wk = (const float*)d_in[3];
    const float* bk = (const float*)d_in[4];
    const float* wv = (const float*)d_in[5];
    const float* bv = (const float*)d_in[6];
    const float* wo = (const float*)d_in[7];
    const float* bo = (const float*)d_in[8];

    unsigned short* ws = (unsigned short*)d_ws;
    unsigned short* xb = ws;                          // 3,145,728 ush
    unsigned short* wqkvT = xb + SEQ * EMB;           // 1,769,472
    unsigned short* woT = wqkvT + 3 * EMB * EMB;      // 589,824
    unsigned short* QKb = woT + EMB * EMB;            // 4096*1536 = 6,291,456
    unsigned short* Vtb = QKb + (size_t)SEQ * 1536;   // 3,145,728
    unsigned short* ctxb = Vtb + HEADS * SEQ * HD;    // 3,145,728
    // attn-phase aliases (xb/wqkvT are dead after gemm128<0>):
    unsigned short* Op = xb;                          // 768 pbs * 4096 = 3,145,728 (exact fit)
    float* mArr = (float*)wqkvT;                      // 49,152 floats
    float* lArr = mArr + 768 * 64;                    // 49,152 floats

    convert_x<<<dim3(SEQ * EMB / 4 / 256), 256, 0, stream>>>(x, xb);
    convert_w<<<dim3(12, 12, 4), 256, 0, stream>>>(wq, wk, wv, wo, wqkvT, woT);
    gemm128<0><<<dim3(SEQ / 128, 3 * EMB / 128), 256, 0, stream>>>(
        xb, wqkvT, bq, bk, bv, QKb, Vtb, nullptr);
    attn_kernel<<<dim3(1152), 256, 0, stream>>>(QKb, Vtb, ctxb, Op, mArr, lArr);
    merge_kernel<<<dim3(384), 256, 0, stream>>>(Op, mArr, lArr, ctxb);
    gemm128<1><<<dim3(SEQ / 128, EMB / 128), 256, 0, stream>>>(
        ctxb, woT, bo, nullptr, nullptr, nullptr, nullptr, (float*)d_out);
}